// Round 8
// baseline (50.263 us; speedup 1.0000x reference)
//
#include <hip/hip_runtime.h>
#include <math.h>

// Problem constants (fixed by setup_inputs)
constexpr int N    = 4;
constexpr int C    = 16;
constexpr int Hin  = 288;
constexpr int Win  = 1216;
constexpr int Hout = 800;
constexpr int Wout = 400;
constexpr int PIX_PER_N = Hout * Wout;       // 320000
constexpr int CH_STRIDE = Hin * Win;         // 350208
constexpr int PIX_PER_BLK = 64;

// Base-grid constants (exact reference f32 values; see round-6 derivation).
constexpr double grd = 0.05 * (800.0 / (double)Hout);        // 0.05 (f64)
constexpr float  GR  = (float)grd;                            // f32(0.05)
constexpr float  CX0 = (float)(-10.0 + grd / 2.0);            // f32(-9.975)
constexpr float  CY0 = (float)( 46.0 - grd / 2.0);            // f32(45.975)

// Register barrier: keeps ops separately rounded exactly where the numpy
// reference's ufuncs are separately rounded (correctness-critical near the
// g2~0 projective singularity).
__device__ __forceinline__ float fbar(float x) {
    asm volatile("" : "+v"(x));
    return x;
}

__global__ __launch_bounds__(256) void bev_sample_kernel(
    const float* __restrict__ x,      // (N, C, Hin, Win)
    const float* __restrict__ theta,  // (N, 3, 3)
    const float* __restrict__ shift,  // (N,)
    float* __restrict__ out)          // (N, C, Hout, Wout)
{
    // Block = 64 pixels x 4 channel-groups. Wave 0 computes the coordinate
    // chain ONCE per pixel (incl. the two IEEE divides) into LDS; all 4
    // waves then gather/combine/store 4 channels each.
    __shared__ int   s_i00[PIX_PER_BLK], s_i01[PIX_PER_BLK];
    __shared__ int   s_i10[PIX_PER_BLK], s_i11[PIX_PER_BLK];
    __shared__ float s_w00[PIX_PER_BLK], s_w01[PIX_PER_BLK];
    __shared__ float s_w10[PIX_PER_BLK], s_w11[PIX_PER_BLK];

    const int tid  = threadIdx.x;
    const int pid0 = blockIdx.x * PIX_PER_BLK;

    if (tid < PIX_PER_BLK) {
        int pid = pid0 + tid;
        int w = pid % Wout;
        int t = pid / Wout;
        int h = t % Hout;
        int n = t / Hout;

        // ---- coordinate chain: bit-exact vs harness np reference ----
        float bx = CX0 + fbar(GR * (float)w);
        float by = CY0 - fbar(GR * (float)h);

        const float* th = theta + n * 9;
        float t00 = th[0], t01 = th[1], t02 = th[2];
        float t10 = th[3], t11 = th[4], t12 = th[5];
        float t20 = th[6], t21 = th[7], t22 = th[8];

        // Einsum flavor F: ascending-k FMA accumulation (matches reference).
        float g0 = fbar(__builtin_fmaf(by, t01, fbar(bx * t00))) + t02;
        float g1 = fbar(__builtin_fmaf(by, t11, fbar(bx * t10))) + t12;
        float g2 = fbar(__builtin_fmaf(by, t21, fbar(bx * t20))) + t22;

        float p0 = g0 / g2;
        float p1 = g1 / g2;

        float gx = fbar(p0 / 608.0f) - 1.0f;
        float gy = fbar((p1 - shift[n]) / 144.0f) - 1.0f;

        float ix = (fbar((gx + 1.0f) * (float)Win) - 1.0f) * 0.5f;
        float iy = (fbar((gy + 1.0f) * (float)Hin) - 1.0f) * 0.5f;

        float ix0f = floorf(ix);
        float iy0f = floorf(iy);
        float wx = ix - ix0f;
        float wy = iy - iy0f;

        int x0 = (int)fminf(fmaxf(ix0f,        0.0f), (float)(Win - 1));
        int x1 = (int)fminf(fmaxf(ix0f + 1.0f, 0.0f), (float)(Win - 1));
        int y0 = (int)fminf(fmaxf(iy0f,        0.0f), (float)(Hin - 1));
        int y1 = (int)fminf(fmaxf(iy0f + 1.0f, 0.0f), (float)(Hin - 1));

        float omwx = 1.0f - wx;
        float omwy = 1.0f - wy;

        s_i00[tid] = y0 * Win + x0;
        s_i01[tid] = y0 * Win + x1;
        s_i10[tid] = y1 * Win + x0;
        s_i11[tid] = y1 * Win + x1;
        s_w00[tid] = omwx * omwy;
        s_w01[tid] = wx * omwy;
        s_w10[tid] = omwx * wy;
        s_w11[tid] = wx * wy;
    }
    __syncthreads();

    const int p  = tid & 63;        // pixel within block (lane id)
    const int cg = tid >> 6;        // channel group = wave id
    const int pid  = pid0 + p;
    const int n    = pid / PIX_PER_N;       // blocks never straddle n
    const int poff = pid - n * PIX_PER_N;   // h*Wout + w

    const int   i00 = s_i00[p], i01 = s_i01[p], i10 = s_i10[p], i11 = s_i11[p];
    const float w00 = s_w00[p], w01 = s_w01[p], w10 = s_w10[p], w11 = s_w11[p];

    const float* xb = x + ((size_t)(n * C + cg * 4)) * CH_STRIDE;

    // Phase 1: 16 independent gathers in flight.
    float v00[4], v01[4], v10[4], v11[4];
    #pragma unroll
    for (int j = 0; j < 4; ++j) {
        const float* pch = xb + (size_t)j * CH_STRIDE;
        v00[j] = pch[i00];
        v01[j] = pch[i01];
        v10[j] = pch[i10];
        v11[j] = pch[i11];
    }

    // Phase 2: combine + streaming stores (write-once output, bypass L2).
    float* ob = out + ((size_t)(n * C + cg * 4)) * PIX_PER_N + poff;
    #pragma unroll
    for (int j = 0; j < 4; ++j) {
        float r = v00[j] * w00 + v01[j] * w01 + v10[j] * w10 + v11[j] * w11;
        __builtin_nontemporal_store(r, ob + (size_t)j * PIX_PER_N);
    }
}

extern "C" void kernel_launch(void* const* d_in, const int* in_sizes, int n_in,
                              void* d_out, int out_size, void* d_ws, size_t ws_size,
                              hipStream_t stream) {
    const float* x     = (const float*)d_in[0];
    const float* theta = (const float*)d_in[1];
    const float* shift = (const float*)d_in[2];
    float* out = (float*)d_out;

    int total_pix = N * Hout * Wout;                 // 1,280,000
    int blocks = total_pix / PIX_PER_BLK;            // 20,000
    bev_sample_kernel<<<blocks, 256, 0, stream>>>(x, theta, shift, out);
}

// Round 9
// 49.659 us; speedup vs baseline: 1.0122x; 1.0122x over previous
//
#include <hip/hip_runtime.h>
#include <math.h>

// Problem constants (fixed by setup_inputs)
constexpr int N    = 4;
constexpr int C    = 16;
constexpr int Hin  = 288;
constexpr int Win  = 1216;
constexpr int Hout = 800;
constexpr int Wout = 400;
constexpr int PIX_PER_N = Hout * Wout;       // 320000
constexpr int CH_STRIDE = Hin * Win;         // 350208
constexpr int PPB  = 64;                     // pixels per block
constexpr int AMAX = 320;                    // max staged bbox texels (nx*ny)

// Base-grid constants (exact reference f32 values; see round-6 derivation).
constexpr double grd = 0.05 * (800.0 / (double)Hout);        // 0.05 (f64)
constexpr float  GR  = (float)grd;                            // f32(0.05)
constexpr float  CX0 = (float)(-10.0 + grd / 2.0);            // f32(-9.975)
constexpr float  CY0 = (float)( 46.0 - grd / 2.0);            // f32(45.975)

// Register barrier: keeps ops separately rounded exactly where the numpy
// reference's ufuncs are separately rounded (correctness-critical near the
// g2~0 projective singularity). Coordinate chain ONLY.
__device__ __forceinline__ float fbar(float x) {
    asm volatile("" : "+v"(x));
    return x;
}

__global__ __launch_bounds__(256) void bev_sample_kernel(
    const float* __restrict__ x,      // (N, C, Hin, Win)
    const float* __restrict__ theta,  // (N, 3, 3)
    const float* __restrict__ shift,  // (N,)
    float* __restrict__ out)          // (N, C, Hout, Wout)
{
    // Block = 64 pixels x 4 channel-groups. Wave 0 computes the bit-exact
    // coordinate chain once per pixel + the block's texel bounding box.
    // If the bbox is small (typical: ~15x3 texels), stage bbox x 16ch into
    // LDS with COALESCED loads and bilinear-combine from LDS -- this
    // replaces 64 divergent wave-gathers per block with ~12 coalesced
    // wave-loads. Rare singular blocks fall back to global gathers.
    __shared__ int   s_x0[PPB], s_x1[PPB], s_y0[PPB], s_y1[PPB];
    __shared__ float s_w00[PPB], s_w01[PPB], s_w10[PPB], s_w11[PPB];
    __shared__ int   s_box[4];              // xlo, nx, ylo, ny
    __shared__ float s_img[AMAX * C];       // 20 KB

    const int tid  = threadIdx.x;
    const int pid0 = blockIdx.x * PPB;
    const int nidx = pid0 / PIX_PER_N;      // blocks never straddle n

    if (tid < PPB) {
        int pid = pid0 + tid;
        int w = pid % Wout;
        int t = pid / Wout;
        int h = t % Hout;
        int n = t / Hout;

        // ---- coordinate chain: bit-exact vs harness np reference ----
        float bx = CX0 + fbar(GR * (float)w);
        float by = CY0 - fbar(GR * (float)h);

        const float* th = theta + n * 9;
        float t00 = th[0], t01 = th[1], t02 = th[2];
        float t10 = th[3], t11 = th[4], t12 = th[5];
        float t20 = th[6], t21 = th[7], t22 = th[8];

        // Einsum flavor F: ascending-k FMA accumulation (matches reference).
        float g0 = fbar(__builtin_fmaf(by, t01, fbar(bx * t00))) + t02;
        float g1 = fbar(__builtin_fmaf(by, t11, fbar(bx * t10))) + t12;
        float g2 = fbar(__builtin_fmaf(by, t21, fbar(bx * t20))) + t22;

        float p0 = g0 / g2;
        float p1 = g1 / g2;

        float gx = fbar(p0 / 608.0f) - 1.0f;
        float gy = fbar((p1 - shift[n]) / 144.0f) - 1.0f;

        float ix = (fbar((gx + 1.0f) * (float)Win) - 1.0f) * 0.5f;
        float iy = (fbar((gy + 1.0f) * (float)Hin) - 1.0f) * 0.5f;

        float ix0f = floorf(ix);
        float iy0f = floorf(iy);
        float wx = ix - ix0f;
        float wy = iy - iy0f;

        int x0 = (int)fminf(fmaxf(ix0f,        0.0f), (float)(Win - 1));
        int x1 = (int)fminf(fmaxf(ix0f + 1.0f, 0.0f), (float)(Win - 1));
        int y0 = (int)fminf(fmaxf(iy0f,        0.0f), (float)(Hin - 1));
        int y1 = (int)fminf(fmaxf(iy0f + 1.0f, 0.0f), (float)(Hin - 1));

        float omwx = 1.0f - wx;
        float omwy = 1.0f - wy;

        s_x0[tid] = x0;  s_x1[tid] = x1;
        s_y0[tid] = y0;  s_y1[tid] = y1;
        s_w00[tid] = omwx * omwy;
        s_w01[tid] = wx * omwy;
        s_w10[tid] = omwx * wy;
        s_w11[tid] = wx * wy;

        // Block bbox over clamped indices (always in-bounds), wave-0 butterfly.
        int xlo = x0, xhi = x1, ylo = y0, yhi = y1;
        #pragma unroll
        for (int m = 1; m < 64; m <<= 1) {
            xlo = min(xlo, __shfl_xor(xlo, m));
            xhi = max(xhi, __shfl_xor(xhi, m));
            ylo = min(ylo, __shfl_xor(ylo, m));
            yhi = max(yhi, __shfl_xor(yhi, m));
        }
        if (tid == 0) {
            s_box[0] = xlo;
            s_box[1] = xhi - xlo + 1;
            s_box[2] = ylo;
            s_box[3] = yhi - ylo + 1;
        }
    }
    __syncthreads();

    const int xlo = s_box[0], nx = s_box[1];
    const int ylo = s_box[2], ny = s_box[3];
    const int area = nx * ny;

    const int p  = tid & 63;        // pixel within block (lane id)
    const int cg = tid >> 6;        // channel group = wave id
    const int poff = pid0 - nidx * PIX_PER_N + p;   // h*Wout + w

    const float w00 = s_w00[p], w01 = s_w01[p], w10 = s_w10[p], w11 = s_w11[p];
    float* ob = out + ((size_t)(nidx * C + cg * 4)) * PIX_PER_N + poff;

    if (area <= AMAX) {
        // ---- staged path: coalesced bbox load -> LDS -> bilinear ----
        const int E = area * C;
        const float* xn = x + (size_t)nidx * C * CH_STRIDE;
        for (int e = tid; e < E; e += 256) {
            int c  = e / area;
            int r  = e - c * area;
            int yy = r / nx;
            int xx = r - yy * nx;
            s_img[e] = xn[(size_t)c * CH_STRIDE + (ylo + yy) * Win + (xlo + xx)];
        }
        __syncthreads();

        const int a00 = (s_y0[p] - ylo) * nx + (s_x0[p] - xlo);
        const int a01 = (s_y0[p] - ylo) * nx + (s_x1[p] - xlo);
        const int a10 = (s_y1[p] - ylo) * nx + (s_x0[p] - xlo);
        const int a11 = (s_y1[p] - ylo) * nx + (s_x1[p] - xlo);

        #pragma unroll
        for (int j = 0; j < 4; ++j) {
            const float* sc = s_img + (cg * 4 + j) * area;
            float r = sc[a00] * w00 + sc[a01] * w01 + sc[a10] * w10 + sc[a11] * w11;
            __builtin_nontemporal_store(r, ob + (size_t)j * PIX_PER_N);
        }
    } else {
        // ---- fallback: per-pixel global gathers (round-8 body) ----
        const int i00 = s_y0[p] * Win + s_x0[p];
        const int i01 = s_y0[p] * Win + s_x1[p];
        const int i10 = s_y1[p] * Win + s_x0[p];
        const int i11 = s_y1[p] * Win + s_x1[p];

        const float* xb = x + ((size_t)(nidx * C + cg * 4)) * CH_STRIDE;
        float v00[4], v01[4], v10[4], v11[4];
        #pragma unroll
        for (int j = 0; j < 4; ++j) {
            const float* pch = xb + (size_t)j * CH_STRIDE;
            v00[j] = pch[i00];
            v01[j] = pch[i01];
            v10[j] = pch[i10];
            v11[j] = pch[i11];
        }
        #pragma unroll
        for (int j = 0; j < 4; ++j) {
            float r = v00[j] * w00 + v01[j] * w01 + v10[j] * w10 + v11[j] * w11;
            __builtin_nontemporal_store(r, ob + (size_t)j * PIX_PER_N);
        }
    }
}

extern "C" void kernel_launch(void* const* d_in, const int* in_sizes, int n_in,
                              void* d_out, int out_size, void* d_ws, size_t ws_size,
                              hipStream_t stream) {
    const float* x     = (const float*)d_in[0];
    const float* theta = (const float*)d_in[1];
    const float* shift = (const float*)d_in[2];
    float* out = (float*)d_out;

    int total_pix = N * Hout * Wout;                 // 1,280,000
    int blocks = total_pix / PPB;                    // 20,000
    bev_sample_kernel<<<blocks, 256, 0, stream>>>(x, theta, shift, out);
}

// Round 10
// 37.354 us; speedup vs baseline: 1.3456x; 1.3294x over previous
//
#include <hip/hip_runtime.h>
#include <math.h>

// Problem constants (fixed by setup_inputs)
constexpr int N    = 4;
constexpr int C    = 16;
constexpr int Hin  = 288;
constexpr int Win  = 1216;
constexpr int Hout = 800;
constexpr int Wout = 400;
constexpr int PIX_PER_N = Hout * Wout;       // 320000
constexpr int CH_STRIDE = Hin * Win;         // 350208

// Base-grid constants (exact reference f32 values; see round-6 derivation).
constexpr double grd = 0.05 * (800.0 / (double)Hout);        // 0.05 (f64)
constexpr float  GR  = (float)grd;                            // f32(0.05)
constexpr float  CX0 = (float)(-10.0 + grd / 2.0);            // f32(-9.975)
constexpr float  CY0 = (float)( 46.0 - grd / 2.0);            // f32(45.975)

// Register barrier: keeps ops separately rounded exactly where the numpy
// reference's ufuncs are separately rounded (correctness-critical near the
// g2~0 projective singularity). Coordinate chain ONLY.
__device__ __forceinline__ float fbar(float x) {
    asm volatile("" : "+v"(x));
    return x;
}

__global__ __launch_bounds__(256) void bev_sample_kernel(
    const float* __restrict__ x,      // (N, C, Hin, Win)
    const float* __restrict__ theta,  // (N, 3, 3)
    const float* __restrict__ shift,  // (N,)
    float* __restrict__ out)          // (N, C, Hout, Wout)
{
    int idx = blockIdx.x * 256 + threadIdx.x;
    if (idx >= N * Hout * Wout) return;

    int w = idx % Wout;
    int t = idx / Wout;
    int h = t % Hout;
    int n = t / Hout;

    // ---- coordinate chain: bit-exact vs harness np reference (round 6) ----
    float bx = CX0 + fbar(GR * (float)w);
    float by = CY0 - fbar(GR * (float)h);

    const float* th = theta + n * 9;
    float t00 = th[0], t01 = th[1], t02 = th[2];
    float t10 = th[3], t11 = th[4], t12 = th[5];
    float t20 = th[6], t21 = th[7], t22 = th[8];

    // Einsum flavor F: ascending-k FMA accumulation (matches the reference).
    float g0 = fbar(__builtin_fmaf(by, t01, fbar(bx * t00))) + t02;
    float g1 = fbar(__builtin_fmaf(by, t11, fbar(bx * t10))) + t12;
    float g2 = fbar(__builtin_fmaf(by, t21, fbar(bx * t20))) + t22;

    float p0 = g0 / g2;
    float p1 = g1 / g2;

    float gx = fbar(p0 / 608.0f) - 1.0f;
    float gy = fbar((p1 - shift[n]) / 144.0f) - 1.0f;

    float ix = (fbar((gx + 1.0f) * (float)Win) - 1.0f) * 0.5f;
    float iy = (fbar((gy + 1.0f) * (float)Hin) - 1.0f) * 0.5f;

    float ix0f = floorf(ix);
    float iy0f = floorf(iy);
    float wx = ix - ix0f;
    float wy = iy - iy0f;

    int x0 = (int)fminf(fmaxf(ix0f,        0.0f), (float)(Win - 1));
    int x1 = (int)fminf(fmaxf(ix0f + 1.0f, 0.0f), (float)(Win - 1));
    int y0 = (int)fminf(fmaxf(iy0f,        0.0f), (float)(Hin - 1));
    int y1 = (int)fminf(fmaxf(iy0f + 1.0f, 0.0f), (float)(Hin - 1));

    float omwx = 1.0f - wx;
    float omwy = 1.0f - wy;
    float w00 = omwx * omwy;
    float w01 = wx * omwy;
    float w10 = omwx * wy;
    float w11 = wx * wy;

    // ---- horizontal corner pairing: one dwordx2 load covers (x0, x1) ----
    // x1 is either x0+1 (interior) or x0 (border-clamped). Load the pair at
    // lb = min(i, CH_STRIDE-2) -- gfx950 global loads support 4B-aligned
    // dwordx2 -- and select:
    //   * normal:               lb==i,   v(x0)=lo, v(x1)= xpair ? hi : lo
    //   * x0==Win-1, y<Hin-1:   lb==i,   hi = next row (unused; xpair=false)
    //   * very last texel:      lb==i-1, v(x0)=hi (avoids 4B OOB), xpair=false
    int lo0 = y0 * Win + x0;
    int lo1 = y1 * Win + x0;
    int lb0 = min(lo0, CH_STRIDE - 2);
    int lb1 = min(lo1, CH_STRIDE - 2);
    bool hi0   = lo0 > lb0;
    bool hi1   = lo1 > lb1;
    bool xpair = x1 > x0;

    const float* xb = x + (size_t)n * C * CH_STRIDE;

    // Phase 1: 32 independent dwordx2 gathers in flight (was 64 dword).
    float2 r0[C], r1[C];
    #pragma unroll
    for (int c = 0; c < C; ++c) {
        const float* pch = xb + (size_t)c * CH_STRIDE;
        r0[c] = *reinterpret_cast<const float2*>(pch + lb0);
        r1[c] = *reinterpret_cast<const float2*>(pch + lb1);
    }

    // Phase 2: select corners, combine, streaming stores.
    size_t obase = ((size_t)(n * C) * Hout + h) * Wout + w;
    #pragma unroll
    for (int c = 0; c < C; ++c) {
        float v00 = hi0   ? r0[c].y : r0[c].x;
        float v01 = xpair ? r0[c].y : v00;
        float v10 = hi1   ? r1[c].y : r1[c].x;
        float v11 = xpair ? r1[c].y : v10;
        float r = v00 * w00 + v01 * w01 + v10 * w10 + v11 * w11;
        __builtin_nontemporal_store(r, &out[obase + (size_t)c * PIX_PER_N]);
    }
}

extern "C" void kernel_launch(void* const* d_in, const int* in_sizes, int n_in,
                              void* d_out, int out_size, void* d_ws, size_t ws_size,
                              hipStream_t stream) {
    const float* x     = (const float*)d_in[0];
    const float* theta = (const float*)d_in[1];
    const float* shift = (const float*)d_in[2];
    float* out = (float*)d_out;

    int total = N * Hout * Wout;  // 1,280,000 pixel threads = 5000 blocks
    int blocks = (total + 255) / 256;
    bev_sample_kernel<<<blocks, 256, 0, stream>>>(x, theta, shift, out);
}